// Round 3
// baseline (416.677 us; speedup 1.0000x reference)
//
#include <hip/hip_runtime.h>
#include <cstdint>

#define ED 256
#define D1 128
#define D2 64
#define NC 50
#define NB 4
#define NN 4096
#define R1 16      // rows per block, mlp kernel
#define TIB 16     // i-rows per block, pair kernel (halves L2 z-traffic vs 8)
#define JT 4       // j per thread, pair kernel
#define PTH 1024   // threads, pair kernel: PTH*JT = NN (full softmax row per block)

// ---------------- Kernel 1: MLP 256 -> 128 -> 64 -> 50, writes zT[b][k][n] + |z|^2 ----------------
__global__ __launch_bounds__(256) void mlp_kernel(
    const float* __restrict__ emb,
    const float* __restrict__ W1, const float* __restrict__ b1,
    const float* __restrict__ W2, const float* __restrict__ b2,
    const float* __restrict__ W3, const float* __restrict__ b3,
    float* __restrict__ zT, float* __restrict__ sq)
{
    __shared__ __align__(16) float se[R1*ED];
    __shared__ __align__(16) float sh1[R1*D1];
    __shared__ __align__(16) float sh2[R1*D2];
    __shared__ __align__(16) float sz[R1*NC];
    const int t = threadIdx.x;
    const long row0 = (long)blockIdx.x * R1;

    // stage 16 embedding rows (contiguous) into LDS, float4
    {
        const float4* g4 = (const float4*)(emb + row0*ED);
        float4* s4 = (float4*)se;
        #pragma unroll
        for (int k = 0; k < (R1*ED/4)/256; k++)
            s4[t + k*256] = g4[t + k*256];
    }
    __syncthreads();

    // layer 1: each thread = one f column, 8 rows
    {
        const int f = t & (D1-1);
        const int half = t >> 7;
        float acc[8];
        const float bias = b1[f];
        #pragma unroll
        for (int rr = 0; rr < 8; rr++) acc[rr] = bias;
        for (int d = 0; d < ED; d += 4) {
            const float w0 = W1[(d+0)*D1 + f];
            const float w1 = W1[(d+1)*D1 + f];
            const float w2 = W1[(d+2)*D1 + f];
            const float w3 = W1[(d+3)*D1 + f];
            #pragma unroll
            for (int rr = 0; rr < 8; rr++) {
                const float4 e = *(const float4*)&se[(half*8+rr)*ED + d];
                acc[rr] = fmaf(e.x, w0, acc[rr]);
                acc[rr] = fmaf(e.y, w1, acc[rr]);
                acc[rr] = fmaf(e.z, w2, acc[rr]);
                acc[rr] = fmaf(e.w, w3, acc[rr]);
            }
        }
        #pragma unroll
        for (int rr = 0; rr < 8; rr++)
            sh1[(half*8+rr)*D1 + f] = fmaxf(acc[rr], 0.0f);
    }
    __syncthreads();

    // layer 2: each thread = one f (0..63), 4 rows
    {
        const int f = t & (D2-1);
        const int g = t >> 6;
        float acc[4];
        const float bias = b2[f];
        #pragma unroll
        for (int rr = 0; rr < 4; rr++) acc[rr] = bias;
        for (int d = 0; d < D1; d += 4) {
            const float w0 = W2[(d+0)*D2 + f];
            const float w1 = W2[(d+1)*D2 + f];
            const float w2_ = W2[(d+2)*D2 + f];
            const float w3 = W2[(d+3)*D2 + f];
            #pragma unroll
            for (int rr = 0; rr < 4; rr++) {
                const float4 h = *(const float4*)&sh1[(g*4+rr)*D1 + d];
                acc[rr] = fmaf(h.x, w0, acc[rr]);
                acc[rr] = fmaf(h.y, w1, acc[rr]);
                acc[rr] = fmaf(h.z, w2_, acc[rr]);
                acc[rr] = fmaf(h.w, w3, acc[rr]);
            }
        }
        #pragma unroll
        for (int rr = 0; rr < 4; rr++)
            sh2[(g*4+rr)*D2 + f] = fmaxf(acc[rr], 0.0f);
    }
    __syncthreads();

    // layer 3: 16 rows x 50 into LDS
    for (int item = t; item < R1*NC; item += 256) {
        const int r = item / NC;
        const int f = item - r*NC;
        float acc = b3[f];
        for (int d = 0; d < D2; d++)
            acc = fmaf(sh2[r*D2 + d], W3[d*NC + f], acc);
        sz[item] = acc;
    }
    __syncthreads();

    // transposed write: for each f, 16 consecutive n -> 64B-contiguous stores
    const int bb = (int)(row0 / NN);
    const int n0 = (int)(row0 - (long)bb*NN);
    for (int idx = t; idx < NC*R1; idx += 256) {
        const int f = idx >> 4;             // R1 = 16
        const int r = idx & 15;
        zT[((size_t)bb*NC + f)*NN + n0 + r] = sz[r*NC + f];
    }

    if (t < R1) {
        float s = 0.0f;
        #pragma unroll
        for (int k = 0; k < NC; k++) { const float v = sz[t*NC + k]; s = fmaf(v, v, s); }
        sq[row0 + t] = s;
    }
}

// ------- Kernel 2: fused pairwise dist -> exp(exp(-d/2)) -> softmax -> +eps renorm -------
// 1024 threads = 16 waves; block owns TIB=16 i-rows x full j-row. Thread t owns j=t*4..t*4+3.
// zj loads double-buffered; VGPR capped at 128 by launch_bounds for 4 waves/SIMD.
__global__ __launch_bounds__(PTH, 4) void pair_kernel(
    const float* __restrict__ zT, const float* __restrict__ sq,
    float* __restrict__ out)
{
    const int t = threadIdx.x;
    const int b = blockIdx.x >> 8;               // / (NN/TIB) = 256
    const int i0 = (blockIdx.x & 255) * TIB;

    __shared__ __align__(16) float szi[NC][TIB]; // z_i fragments, k-major (broadcast reads)
    __shared__ float ssqi[TIB];
    __shared__ float wsum[PTH/64][TIB];
    __shared__ float sS[TIB];

    const float* ztb = zT + (size_t)b * NC * NN;
    const float* sqb = sq + (size_t)b * NN;

    for (int idx = t; idx < NC*TIB; idx += PTH) {
        const int k = idx >> 4, ii = idx & 15;
        szi[k][ii] = ztb[(size_t)k*NN + i0 + ii];
    }
    if (t < TIB) ssqi[t] = sqb[i0 + t];
    __syncthreads();

    float acc[TIB][JT];
    #pragma unroll
    for (int ii = 0; ii < TIB; ii++)
        #pragma unroll
        for (int jj = 0; jj < JT; jj++) acc[ii][jj] = 0.0f;

    const int j0 = t * 4;
    // double-buffered k loop; k=49's prefetch reads row 50 (= sq region, valid ws memory, unused)
    float4 zj = *(const float4*)(ztb + j0);
    for (int k = 0; k < NC; k++) {
        const float4 zjn = *(const float4*)(ztb + (size_t)(k+1)*NN + j0);
        const float4 zia = *(const float4*)&szi[k][0];   // wave-uniform -> LDS broadcast
        const float4 zib = *(const float4*)&szi[k][4];
        const float4 zic = *(const float4*)&szi[k][8];
        const float4 zid = *(const float4*)&szi[k][12];
        const float zi[16] = {zia.x, zia.y, zia.z, zia.w, zib.x, zib.y, zib.z, zib.w,
                              zic.x, zic.y, zic.z, zic.w, zid.x, zid.y, zid.z, zid.w};
        const float zjv[4] = {zj.x, zj.y, zj.z, zj.w};
        #pragma unroll
        for (int ii = 0; ii < TIB; ii++)
            #pragma unroll
            for (int jj = 0; jj < JT; jj++)
                acc[ii][jj] = fmaf(zi[ii], zjv[jj], acc[ii][jj]);
        zj = zjn;
    }

    const float4 sj4 = *(const float4*)(sqb + j0);
    const float sqj[4] = {sj4.x, sj4.y, sj4.z, sj4.w};

    // dist -> e = exp(exp(-d/2)) in place, accumulate row sums
    float rsum[TIB];
    #pragma unroll
    for (int ii = 0; ii < TIB; ii++) {
        const float sqi = ssqi[ii];                      // LDS broadcast
        float s = 0.0f;
        #pragma unroll
        for (int jj = 0; jj < JT; jj++) {
            const float d = fmaxf(sqi + sqj[jj] - 2.0f*acc[ii][jj], 0.0f);
            const float e = __expf(__expf(-0.5f*d));
            acc[ii][jj] = e;
            s += e;
        }
        rsum[ii] = s;
    }

    // reduce rsum[16] across block: wave shfl -> LDS -> final
    #pragma unroll
    for (int off = 32; off; off >>= 1)
        #pragma unroll
        for (int ii = 0; ii < TIB; ii++)
            rsum[ii] += __shfl_xor(rsum[ii], off, 64);
    const int wave = t >> 6, lane = t & 63;
    if (lane == 0) {
        #pragma unroll
        for (int ii = 0; ii < TIB; ii++) wsum[wave][ii] = rsum[ii];
    }
    __syncthreads();
    if (t < TIB) {
        float s = 0.0f;
        #pragma unroll
        for (int w = 0; w < PTH/64; w++) s += wsum[w][t];
        sS[t] = s;
    }
    __syncthreads();

    const float rn = 1.0f / (1.0f + (float)NN * 1e-6f);
    const float c = 1e-6f * rn;
    float* ob = out + ((size_t)(b*NN + i0)) * NN + j0;
    #pragma unroll
    for (int ii = 0; ii < TIB; ii++) {
        const float is = rn / sS[ii];                    // LDS broadcast
        float4 v;
        v.x = fmaf(acc[ii][0], is, c);
        v.y = fmaf(acc[ii][1], is, c);
        v.z = fmaf(acc[ii][2], is, c);
        v.w = fmaf(acc[ii][3], is, c);
        *(float4*)(ob + (size_t)ii*NN) = v;              // coalesced 1KB/wave
    }
}

extern "C" void kernel_launch(void* const* d_in, const int* in_sizes, int n_in,
                              void* d_out, int out_size, void* d_ws, size_t ws_size,
                              hipStream_t stream) {
    const float* emb = (const float*)d_in[0];
    const float* W1  = (const float*)d_in[1];
    const float* b1  = (const float*)d_in[2];
    const float* W2  = (const float*)d_in[3];
    const float* b2  = (const float*)d_in[4];
    const float* W3  = (const float*)d_in[5];
    const float* b3  = (const float*)d_in[6];
    float* out = (float*)d_out;

    float* zT = (float*)d_ws;                       // NB*NC*NN floats (transposed)
    float* sq = zT + (size_t)NB*NC*NN;              // NB*NN floats

    mlp_kernel<<<NB*NN/R1, 256, 0, stream>>>(emb, W1, b1, W2, b2, W3, b3, zT, sq);
    pair_kernel<<<NB*(NN/TIB), PTH, 0, stream>>>(zT, sq, out);
}